// Round 12
// baseline (420.080 us; speedup 1.0000x reference)
//
#include <hip/hip_runtime.h>
#include <hip/hip_bf16.h>

#define DEVFN __device__ __forceinline__

using short8 = __attribute__((ext_vector_type(8))) short;
using f32x4  = __attribute__((ext_vector_type(4))) float;

// ---- dual-dtype helpers: flags[0]=1 -> floats are f32 (else bf16);
//                          flags[1]=1 -> ints are int64 (else int32)
DEVFN float ldf(const void* p, size_t i, bool f32) {
    return f32 ? ((const float*)p)[i]
               : __bfloat162float(((const __hip_bfloat16*)p)[i]);
}
DEVFN int ldidx(const void* p, size_t i, bool i64) {
    return i64 ? (int)((const long long*)p)[i] : ((const int*)p)[i];
}
DEVFN void stf(void* p, size_t i, float v, bool f32) {
    if (f32) ((float*)p)[i] = v;
    else     ((__hip_bfloat16*)p)[i] = __float2bfloat16(v);
}
DEVFN float lky(float v) { return v > 0.f ? v : 0.2f * v; }

// raw-bits bf16 <-> f32
DEVFN float bfbits2f(short s) {
    return __uint_as_float(((unsigned)(unsigned short)s) << 16);
}
DEVFN short f2bfbits(float f) {  // RNE, finite inputs
    unsigned u = __float_as_uint(f);
    return (short)((u + 0x7fffu + ((u >> 16) & 1u)) >> 16);
}

__global__ void detect_k(const void* x, const void* ei, int* flags) {
    if (threadIdx.x == 0 && blockIdx.x == 0) {
        const __hip_bfloat16* xb = (const __hip_bfloat16*)x;
        int bad = 0;
        for (int i = 0; i < 512; ++i) {
            float v = __bfloat162float(xb[i]);
            if (!(v == v) || fabsf(v) > 1.0e6f) bad++;
        }
        flags[0] = (bad > 16) ? 1 : 0;
        const unsigned* w = (const unsigned*)ei;
        int zeros = 0;
        for (int i = 0; i < 64; ++i) if (w[2 * i + 1] == 0u) zeros++;
        flags[1] = (zeros >= 60) ? 1 : 0;
    }
}

__global__ void zero_i32(int* __restrict__ p, int n) {
    int i = blockIdx.x * blockDim.x + threadIdx.x;
    int st = gridDim.x * blockDim.x;
    for (; i < n; i += st) p[i] = 0;
}
__global__ void zero_f32(float* __restrict__ p, long n) {
    long i = (long)blockIdx.x * blockDim.x + threadIdx.x;
    long st = (long)gridDim.x * blockDim.x;
    for (; i < n; i += st) p[i] = 0.f;
}

// ---------------- CSR build: bucketed two-pass (dst-sorted {src, eid}) ----------------
// hist: per-node counts + per-bucket (128 nodes, d>>7) counts (padded x16 ints)
__global__ void hist_k(const void* __restrict__ ei, int E, int* __restrict__ cnt,
                       int* __restrict__ bcnt, const int* __restrict__ flags) {
    const bool i64 = flags[1] != 0;
    int e = blockIdx.x * blockDim.x + threadIdx.x;
    if (e >= E) return;
    int d = ldidx(ei, (size_t)E + e, i64);
    atomicAdd(&cnt[d], 1);
    atomicAdd(&bcnt[(d >> 7) * 16], 1);
}

__global__ void scan_block_k(const int* __restrict__ cnt, int* __restrict__ incl,
                             int* __restrict__ part, int N) {
    __shared__ int sm[256];
    int tid = threadIdx.x;
    int i = blockIdx.x * 256 + tid;
    int v = (i < N) ? cnt[i] : 0;
    sm[tid] = v;
    __syncthreads();
    for (int o = 1; o < 256; o <<= 1) {
        int t = (tid >= o) ? sm[tid - o] : 0;
        __syncthreads();
        sm[tid] += t;
        __syncthreads();
    }
    if (i < N) incl[i] = sm[tid];
    if (tid == 255) part[blockIdx.x] = sm[255];
}

__global__ void scan_part_k(int* __restrict__ part, int nb) {
    __shared__ int sm[256];
    __shared__ int off;
    int tid = threadIdx.x;
    if (tid == 0) off = 0;
    __syncthreads();
    for (int b = 0; b < nb; b += 256) {
        int i = b + tid;
        int v = (i < nb) ? part[i] : 0;
        sm[tid] = v;
        __syncthreads();
        for (int o = 1; o < 256; o <<= 1) {
            int t = (tid >= o) ? sm[tid - o] : 0;
            __syncthreads();
            sm[tid] += t;
            __syncthreads();
        }
        if (i < nb) part[i] = sm[tid] - v + off;
        __syncthreads();
        if (tid == 255) off += sm[255];
        __syncthreads();
    }
}

__global__ void finalize_scan_k(int* __restrict__ incl_cur, const int* __restrict__ cnt,
                                const int* __restrict__ part, int* __restrict__ rs,
                                int N, int E) {
    int i = blockIdx.x * 256 + threadIdx.x;
    if (i >= N) return;
    int v = incl_cur[i] - cnt[i] + part[blockIdx.x];
    rs[i] = v;
    incl_cur[i] = v;
    if (i == N - 1) rs[N] = E;
}

// exclusive scan of padded bucket counts -> bbase (dense) + bcur (padded)
__global__ void bucket_scan_k(const int* __restrict__ bcnt, int* __restrict__ bbase,
                              int* __restrict__ bcur, int NB, int E) {
    __shared__ int sm[256];
    __shared__ int off;
    int tid = threadIdx.x;
    if (tid == 0) off = 0;
    __syncthreads();
    for (int b = 0; b < NB; b += 256) {
        int i = b + tid;
        int v = (i < NB) ? bcnt[i * 16] : 0;
        sm[tid] = v;
        __syncthreads();
        for (int o = 1; o < 256; o <<= 1) {
            int t = (tid >= o) ? sm[tid - o] : 0;
            __syncthreads();
            sm[tid] += t;
            __syncthreads();
        }
        if (i < NB) { int ex = sm[tid] - v + off; bbase[i] = ex; bcur[i * 16] = ex; }
        __syncthreads();
        if (tid == 255) off += sm[255];
        __syncthreads();
    }
    if (tid == 0) bbase[NB] = E;
}

// pass A: edges -> bucket-contiguous staging (sequential fill per bucket => L2-hot lines)
__global__ void bucket_scatter_k(const void* __restrict__ ei, int E, int* __restrict__ bcur,
                                 int4* __restrict__ bk, const int* __restrict__ flags) {
    const bool i64 = flags[1] != 0;
    int e = blockIdx.x * blockDim.x + threadIdx.x;
    if (e >= E) return;
    int s = ldidx(ei, e, i64);
    int d = ldidx(ei, (size_t)E + e, i64);
    int p = atomicAdd(&bcur[(d >> 7) * 16], 1);
    bk[p] = make_int4(s, d, e, 0);
}

// pass B: one block per bucket; coalesced bk read, hot cur/csr windows
__global__ void final_scatter_k(const int4* __restrict__ bk, const int* __restrict__ bbase,
                                int* __restrict__ cur, int2* __restrict__ csr, int NB) {
    int b = blockIdx.x;
    if (b >= NB) return;
    const int beg = bbase[b], end = bbase[b + 1];
    for (int i = beg + threadIdx.x; i < end; i += blockDim.x) {
        int4 v = bk[i];
        int p = atomicAdd(&cur[v.y], 1);
        csr[p] = make_int2(v.x, v.z);
    }
}

// ---------------- MFMA GEMM: h = A @ W, fused alpha dots (verbatim round 6/7) ----------------
template <int DSRC, int FOUT, int HEADS>
__global__ __launch_bounds__(256) void gemm_alpha_mfma_k(
    const void* __restrict__ xin, const void* __restrict__ Wv,
    const void* __restrict__ asv, const void* __restrict__ adv,
    short* __restrict__ h_bf, float* __restrict__ as_out, float* __restrict__ ad_out,
    int N, const int* __restrict__ flags)
{
    constexpr int FIN = 128;
    constexpr int NCT = FOUT / 16;
    constexpr int CPH = FOUT / HEADS;
    constexpr int CTPH = CPH / 16;
    const bool f32 = flags[0] != 0;

    __shared__ short Wt[FOUT * FIN];    // swizzled, col-major

    for (int i = threadIdx.x; i < FIN * FOUT; i += 256) {
        int k = i / FOUT, c = i - (i / FOUT) * FOUT;
        short w;
        if (f32) w = f2bfbits(((const float*)Wv)[i]);
        else     w = ((const short*)Wv)[i];
        *(short*)((char*)Wt + (size_t)c * (FIN * 2) + (((k * 2) ^ ((c & 7) << 4)))) = w;
    }
    __syncthreads();

    const int wv = threadIdx.x >> 6;
    const int lane = threadIdx.x & 63;
    const int m0 = blockIdx.x * 64 + wv * 16;
    if (m0 >= N) return;
    const int lrow = lane & 15;
    const int lk   = lane >> 4;

    short8 afrag[4];
    if (DSRC == 0 && f32) {
        const float* xf = (const float*)xin + (size_t)(m0 + lrow) * FIN + lk * 8;
#pragma unroll
        for (int ks = 0; ks < 4; ++ks) {
            short8 t;
#pragma unroll
            for (int j = 0; j < 8; ++j) t[j] = f2bfbits(xf[ks * 32 + j]);
            afrag[ks] = t;
        }
    } else {
        const short* xb = (const short*)xin + (size_t)(m0 + lrow) * FIN + lk * 8;
#pragma unroll
        for (int ks = 0; ks < 4; ++ks)
            afrag[ks] = *(const short8*)(xb + ks * 32);
    }

    float csA[HEADS][4], cdA[HEADS][4];
#pragma unroll
    for (int hd = 0; hd < HEADS; ++hd)
#pragma unroll
        for (int r = 0; r < 4; ++r) { csA[hd][r] = 0.f; cdA[hd][r] = 0.f; }

#pragma unroll
    for (int ct = 0; ct < NCT; ++ct) {
        const int col = ct * 16 + lrow;
        const int hd = ct / CTPH;
        f32x4 acc = {0.f, 0.f, 0.f, 0.f};
#pragma unroll
        for (int ks = 0; ks < 4; ++ks) {
            const int kbyte = ks * 64 + lk * 16;
            short8 bfrag = *(const short8*)((const char*)Wt +
                               (size_t)col * (FIN * 2) + (kbyte ^ ((col & 7) << 4)));
            acc = __builtin_amdgcn_mfma_f32_16x16x32_bf16(afrag[ks], bfrag, acc, 0, 0, 0);
        }
        const float asc = ldf(asv, col, f32);
        const float adc = ldf(adv, col, f32);
#pragma unroll
        for (int r = 0; r < 4; ++r) {
            h_bf[(size_t)(m0 + lk * 4 + r) * FOUT + col] = f2bfbits(acc[r]);
            csA[hd][r] += acc[r] * asc;
            cdA[hd][r] += acc[r] * adc;
        }
    }

#pragma unroll
    for (int hd = 0; hd < HEADS; ++hd)
#pragma unroll
        for (int r = 0; r < 4; ++r) {
            float cs = csA[hd][r], cd = cdA[hd][r];
            for (int o = 1; o < 16; o <<= 1) {
                cs += __shfl_xor(cs, o);
                cd += __shfl_xor(cd, o);
            }
            csA[hd][r] = cs; cdA[hd][r] = cd;
        }
    if (lrow == 0) {
#pragma unroll
        for (int r = 0; r < 4; ++r) {
            int n = m0 + lk * 4 + r;
#pragma unroll
            for (int hd = 0; hd < HEADS; ++hd) {
                as_out[(size_t)n * HEADS + hd] = csA[hd][r];
                ad_out[(size_t)n * HEADS + hd] = cdA[hd][r];
            }
        }
    }
}

// ---------------- FUSED softmax + pull, FOUT=128, wave per node (verbatim round 11) ----------------
template <int HEADS, bool RELU>
__global__ __launch_bounds__(256) void agg128_k(
    const short* __restrict__ h_bf, const float* __restrict__ as_,
    const float* __restrict__ ad_, const int* __restrict__ rs,
    const int2* __restrict__ csr, const void* __restrict__ bias,
    short* __restrict__ z_bf, void* __restrict__ dout, size_t aoff,
    int N, const int* __restrict__ flags)
{
    __shared__ int   ls_src[4][64];
    __shared__ float ls_a[4][HEADS][64];
    const bool f32 = flags[0] != 0;
    const int wv = threadIdx.x >> 6;
    const int wid = (blockIdx.x * 256 + threadIdx.x) >> 6;
    if (wid >= N) return;
    const int lane = threadIdx.x & 63;
    const int beg = rs[wid], end = rs[wid + 1];
    const int deg = end - beg;
    const int cg = lane & 15;     // col-group: cols cg*8 .. cg*8+7
    const int es = lane >> 4;     // edge slot 0..3
    const int h = (HEADS == 2) ? (cg >> 3) : 0;

    const float ad0 = ad_[(size_t)wid * HEADS];
    const float ad1 = (HEADS == 2) ? ad_[(size_t)wid * HEADS + 1] : 0.f;

    float acc[8] = {0.f, 0.f, 0.f, 0.f, 0.f, 0.f, 0.f, 0.f};

    if (deg <= 64) {
        const bool act = lane < deg;
        int2 se = make_int2(0, 0);
        if (act) se = csr[beg + lane];
        float l0 = act ? lky(as_[(size_t)se.x * HEADS] + ad0) : -1e30f;
        float l1 = 0.f;
        if (HEADS == 2) l1 = act ? lky(as_[(size_t)se.x * HEADS + 1] + ad1) : -1e30f;

        float m0 = l0, m1 = l1;
        for (int o = 1; o < 64; o <<= 1) {
            m0 = fmaxf(m0, __shfl_xor(m0, o));
            if (HEADS == 2) m1 = fmaxf(m1, __shfl_xor(m1, o));
        }
        float e0 = act ? expf(l0 - m0) : 0.f;
        float e1 = (HEADS == 2) ? (act ? expf(l1 - m1) : 0.f) : 0.f;
        float s0 = e0, s1 = e1;
        for (int o = 1; o < 64; o <<= 1) {
            s0 += __shfl_xor(s0, o);
            if (HEADS == 2) s1 += __shfl_xor(s1, o);
        }
        if (act) {
            float a0 = e0 * (1.f / (s0 + 1e-16f));
            ls_src[wv][lane] = se.x;
            ls_a[wv][0][lane] = a0;
            stf(dout, aoff + (size_t)se.y * HEADS, a0, f32);
            if (HEADS == 2) {
                float a1 = e1 * (1.f / (s1 + 1e-16f));
                ls_a[wv][1][lane] = a1;
                stf(dout, aoff + (size_t)se.y * 2 + 1, a1, f32);
            }
        }
        for (int b = 0; b < deg; b += 8) {
            const int pA = b + es, pB = b + 4 + es;
            int sA = 0, sB = 0;
            float aA = 0.f, aB = 0.f;
            if (pA < deg) { sA = ls_src[wv][pA]; aA = ls_a[wv][h][pA]; }
            if (pB < deg) { sB = ls_src[wv][pB]; aB = ls_a[wv][h][pB]; }
            const short8 hA = *(const short8*)(h_bf + (size_t)sA * 128 + cg * 8);
            const short8 hB = *(const short8*)(h_bf + (size_t)sB * 128 + cg * 8);
#pragma unroll
            for (int j = 0; j < 8; ++j) acc[j] = fmaf(bfbits2f(hA[j]), aA, acc[j]);
#pragma unroll
            for (int j = 0; j < 8; ++j) acc[j] = fmaf(bfbits2f(hB[j]), aB, acc[j]);
        }
    } else {
        float m0 = -1e30f, m1 = -1e30f;
        for (int p = beg + lane; p < end; p += 64) {
            int s = csr[p].x;
            m0 = fmaxf(m0, lky(as_[(size_t)s * HEADS] + ad0));
            if (HEADS == 2) m1 = fmaxf(m1, lky(as_[(size_t)s * HEADS + 1] + ad1));
        }
        for (int o = 1; o < 64; o <<= 1) {
            m0 = fmaxf(m0, __shfl_xor(m0, o));
            if (HEADS == 2) m1 = fmaxf(m1, __shfl_xor(m1, o));
        }
        float s0 = 0.f, s1 = 0.f;
        for (int p = beg + lane; p < end; p += 64) {
            int s = csr[p].x;
            s0 += expf(lky(as_[(size_t)s * HEADS] + ad0) - m0);
            if (HEADS == 2) s1 += expf(lky(as_[(size_t)s * HEADS + 1] + ad1) - m1);
        }
        for (int o = 1; o < 64; o <<= 1) {
            s0 += __shfl_xor(s0, o);
            if (HEADS == 2) s1 += __shfl_xor(s1, o);
        }
        const float inv0 = 1.f / (s0 + 1e-16f);
        const float inv1 = 1.f / (s1 + 1e-16f);

        for (int cb = beg; cb < end; cb += 64) {
            const int cn = min(64, end - cb);
            if (lane < cn) {
                int2 se = csr[cb + lane];
                float a0 = expf(lky(as_[(size_t)se.x * HEADS] + ad0) - m0) * inv0;
                ls_src[wv][lane] = se.x;
                ls_a[wv][0][lane] = a0;
                stf(dout, aoff + (size_t)se.y * HEADS, a0, f32);
                if (HEADS == 2) {
                    float a1 = expf(lky(as_[(size_t)se.x * HEADS + 1] + ad1) - m1) * inv1;
                    ls_a[wv][1][lane] = a1;
                    stf(dout, aoff + (size_t)se.y * 2 + 1, a1, f32);
                }
            }
            for (int b = 0; b < cn; b += 8) {
                const int pA = b + es, pB = b + 4 + es;
                int sA = 0, sB = 0;
                float aA = 0.f, aB = 0.f;
                if (pA < cn) { sA = ls_src[wv][pA]; aA = ls_a[wv][h][pA]; }
                if (pB < cn) { sB = ls_src[wv][pB]; aB = ls_a[wv][h][pB]; }
                const short8 hA = *(const short8*)(h_bf + (size_t)sA * 128 + cg * 8);
                const short8 hB = *(const short8*)(h_bf + (size_t)sB * 128 + cg * 8);
#pragma unroll
                for (int j = 0; j < 8; ++j) acc[j] = fmaf(bfbits2f(hA[j]), aA, acc[j]);
#pragma unroll
                for (int j = 0; j < 8; ++j) acc[j] = fmaf(bfbits2f(hB[j]), aB, acc[j]);
            }
        }
    }

#pragma unroll
    for (int j = 0; j < 8; ++j) {
        acc[j] += __shfl_xor(acc[j], 16);
        acc[j] += __shfl_xor(acc[j], 32);
    }
    if (es == 0) {
        short8 outv;
#pragma unroll
        for (int j = 0; j < 8; ++j) {
            float v = acc[j] + ldf(bias, cg * 8 + j, f32);
            if (RELU) v = fmaxf(v, 0.f);
            outv[j] = f2bfbits(v);
        }
        *(short8*)(z_bf + (size_t)wid * 128 + cg * 8) = outv;
    }
}

// ---------------- FUSED softmax + pull, FOUT=16, wave per node (verbatim round 11) ----------------
__global__ __launch_bounds__(256) void agg16_k(
    const short* __restrict__ h_bf, const float* __restrict__ as_,
    const float* __restrict__ ad_, const int* __restrict__ rs,
    const int2* __restrict__ csr, float* __restrict__ out,
    void* __restrict__ dout, size_t aoff, int N, const int* __restrict__ flags)
{
    __shared__ int   ls_src[4][64];
    __shared__ float ls_a[4][64];
    const bool f32 = flags[0] != 0;
    const int wv = threadIdx.x >> 6;
    const int wid = (blockIdx.x * 256 + threadIdx.x) >> 6;
    if (wid >= N) return;
    const int lane = threadIdx.x & 63;
    const int beg = rs[wid], end = rs[wid + 1];
    const int deg = end - beg;
    const int cg = lane & 7;      // cols cg*2, cg*2+1
    const int es = lane >> 3;     // edge slot 0..7

    const float ad0 = ad_[wid];

    float a0s = 0.f, a1s = 0.f;

    if (deg <= 64) {
        const bool act = lane < deg;
        int2 se = make_int2(0, 0);
        if (act) se = csr[beg + lane];
        float l0 = act ? lky(as_[se.x] + ad0) : -1e30f;
        float m0 = l0;
        for (int o = 1; o < 64; o <<= 1) m0 = fmaxf(m0, __shfl_xor(m0, o));
        float e0 = act ? expf(l0 - m0) : 0.f;
        float s0 = e0;
        for (int o = 1; o < 64; o <<= 1) s0 += __shfl_xor(s0, o);
        if (act) {
            float a0 = e0 * (1.f / (s0 + 1e-16f));
            ls_src[wv][lane] = se.x;
            ls_a[wv][lane] = a0;
            stf(dout, aoff + se.y, a0, f32);
        }
        for (int b = 0; b < deg; b += 8) {
            const int p = b + es;
            if (p < deg) {
                const int sj = ls_src[wv][p];
                const float a = ls_a[wv][p];
                const int hv = *(const int*)(h_bf + (size_t)sj * 16 + cg * 2);
                a0s = fmaf(bfbits2f((short)(hv & 0xffff)), a, a0s);
                a1s = fmaf(bfbits2f((short)(hv >> 16)), a, a1s);
            }
        }
    } else {
        float m0 = -1e30f;
        for (int p = beg + lane; p < end; p += 64)
            m0 = fmaxf(m0, lky(as_[csr[p].x] + ad0));
        for (int o = 1; o < 64; o <<= 1) m0 = fmaxf(m0, __shfl_xor(m0, o));
        float s0 = 0.f;
        for (int p = beg + lane; p < end; p += 64)
            s0 += expf(lky(as_[csr[p].x] + ad0) - m0);
        for (int o = 1; o < 64; o <<= 1) s0 += __shfl_xor(s0, o);
        const float inv0 = 1.f / (s0 + 1e-16f);

        for (int cb = beg; cb < end; cb += 64) {
            const int cn = min(64, end - cb);
            if (lane < cn) {
                int2 se = csr[cb + lane];
                float a0 = expf(lky(as_[se.x] + ad0) - m0) * inv0;
                ls_src[wv][lane] = se.x;
                ls_a[wv][lane] = a0;
                stf(dout, aoff + se.y, a0, f32);
            }
            for (int b = 0; b < cn; b += 8) {
                const int p = b + es;
                if (p < cn) {
                    const int sj = ls_src[wv][p];
                    const float a = ls_a[wv][p];
                    const int hv = *(const int*)(h_bf + (size_t)sj * 16 + cg * 2);
                    a0s = fmaf(bfbits2f((short)(hv & 0xffff)), a, a0s);
                    a1s = fmaf(bfbits2f((short)(hv >> 16)), a, a1s);
                }
            }
        }
    }

#pragma unroll
    for (int o = 8; o < 64; o <<= 1) {
        a0s += __shfl_xor(a0s, o);
        a1s += __shfl_xor(a1s, o);
    }
    if (es == 0) {
        out[(size_t)wid * 16 + cg * 2]     = a0s;
        out[(size_t)wid * 16 + cg * 2 + 1] = a1s;
    }
}

// layer3 finalize: emb = acc + b3, write emb to d_out, pool per-graph sums
__global__ __launch_bounds__(256) void finalize3_k(
    const float* __restrict__ acc, const void* __restrict__ bias,
    const void* __restrict__ batch, void* __restrict__ dout, size_t emb_off,
    float* __restrict__ g_sum, int N, const int* __restrict__ flags)
{
    const bool f32 = flags[0] != 0;
    const bool i64 = flags[1] != 0;
    __shared__ float gp[256];
    int tid = threadIdx.x;
    gp[tid] = 0.f;
    __syncthreads();
    long idx = (long)blockIdx.x * 256 + tid;
    if (idx < (long)N * 16) {
        int n = (int)(idx >> 4), col = (int)(idx & 15);
        float v = acc[idx] + ldf(bias, col, f32);
        stf(dout, emb_off + idx, v, f32);
        int g = ldidx(batch, n, i64);
        atomicAdd(&gp[g * 16 + col], v);
    }
    __syncthreads();
    float pv = gp[tid];
    if (pv != 0.f) atomicAdd(&g_sum[tid], pv);
}

__global__ __launch_bounds__(256) void head_k(
    const float* __restrict__ g_sum, const void* __restrict__ batch,
    const void* __restrict__ Wl, const void* __restrict__ bl,
    void* __restrict__ dout, size_t gemb_off, int N, const int* __restrict__ flags)
{
    const bool f32 = flags[0] != 0;
    const bool i64 = flags[1] != 0;
    __shared__ float ge[256];
    __shared__ int cnts[16];
    int tid = threadIdx.x;
    if (tid < 16) {
        int lo = 0, hi = N;
        while (lo < hi) { int mid = (lo + hi) >> 1; if (ldidx(batch, mid, i64) < tid) lo = mid + 1; else hi = mid; }
        int l2 = 0, h2 = N;
        while (l2 < h2) { int mid = (l2 + h2) >> 1; if (ldidx(batch, mid, i64) <= tid) l2 = mid + 1; else h2 = mid; }
        cnts[tid] = l2 - lo;
    }
    __syncthreads();
    {
        int g = tid >> 4;
        float v = g_sum[tid] / fmaxf((float)cnts[g], 1.f);
        ge[tid] = v;
        stf(dout, gemb_off + tid, v, f32);
    }
    __syncthreads();
    if (tid < 32) {
        int g = tid >> 1, j = tid & 1;
        float s = ldf(bl, j, f32);
        for (int c = 0; c < 16; ++c) s += ge[g * 16 + c] * ldf(Wl, (size_t)c * 2 + j, f32);
        stf(dout, (size_t)g * 2 + j, s, f32);
    }
}

static inline int cdiv(long a, int b) { return (int)((a + b - 1) / b); }

extern "C" void kernel_launch(void* const* d_in, const int* in_sizes, int n_in,
                              void* d_out, int out_size, void* d_ws, size_t ws_size,
                              hipStream_t stream)
{
    const void* x   = d_in[0];
    const void* ei  = d_in[1];
    const void* batch = d_in[2];
    const void* W1  = d_in[3];
    const void* as1 = d_in[4];
    const void* ad1 = d_in[5];
    const void* b1  = d_in[6];
    const void* W2  = d_in[7];
    const void* as2 = d_in[8];
    const void* ad2 = d_in[9];
    const void* b2  = d_in[10];
    const void* W3  = d_in[11];
    const void* as3 = d_in[12];
    const void* ad3 = d_in[13];
    const void* b3  = d_in[14];
    const void* Wl  = d_in[15];
    const void* bl  = d_in[16];

    const int N = in_sizes[0] / 128;
    const int E = in_sizes[1] / 2;
    const int NB = (N + 127) >> 7;     // 128-node buckets

    int* flags = (int*)d_ws;
    float* ws = (float*)d_ws + 16;
    size_t o = 0;
    float* as_  = ws + o; o += (size_t)N * 2;
    float* ad_  = ws + o; o += (size_t)N * 2;
    float* bufE = ws + o; o += (size_t)N * 16;
    float* g_sum = ws + o; o += 256;
    short* hX = (short*)(ws + o); o += (size_t)N * 64;  // h (bf16), gemm out
    short* hZ = (short*)(ws + o); o += (size_t)N * 64;  // z (bf16), agg out
    short* h3 = (short*)(ws + o); o += (size_t)N * 8;   // layer3 h (bf16)
    int* ip = (int*)(ws + o);
    int* cnt   = ip;           ip += N;
    int* bcnt  = ip;           ip += NB * 16;  // padded x16 (contiguous after cnt for one zero pass)
    int* incl  = ip;           ip += N;        // reused as `cur` after finalize_scan
    int* part  = ip;           ip += 256;
    int* rs    = ip;           ip += N + 1;
    int* bbase = ip;           ip += NB + 1;
    int* bcur  = ip;           ip += NB * 16;  // padded x16
    if (((uintptr_t)ip & 15) != 0) ip += 4 - (((uintptr_t)ip >> 2) & 3);   // align int4
    int4* bk = (int4*)ip;      ip += 4 * (size_t)E;   // bucket staging {s, d, e, pad}
    int2* csr = (int2*)ip;     ip += 2 * (size_t)E;   // packed {src, eid}, dst-sorted

    const size_t off_gemb = 32;
    const size_t off_emb  = 32 + 256;
    const size_t off_a1   = off_emb + (size_t)N * 16;
    const size_t off_a2   = off_a1 + (size_t)E * 2;
    const size_t off_a3   = off_a2 + (size_t)E;

    const int B = 256;
    const int nbN = cdiv(N, 256);
    const int gemmBlocks = cdiv(N, 64);
    const int waveBlocks = cdiv(N, 4);   // 4 waves (nodes) per 256-thr block

    detect_k<<<1, 64, 0, stream>>>(x, ei, flags);

    // ---- CSR build: hist -> node scan; bucket scan -> 2-pass scatter ----
    zero_i32<<<cdiv(N + NB * 16, B), B, 0, stream>>>(cnt, N + NB * 16);  // cnt + bcnt
    hist_k<<<cdiv(E, B), B, 0, stream>>>(ei, E, cnt, bcnt, flags);
    scan_block_k<<<nbN, B, 0, stream>>>(cnt, incl, part, N);
    scan_part_k<<<1, B, 0, stream>>>(part, nbN);
    finalize_scan_k<<<nbN, B, 0, stream>>>(incl, cnt, part, rs, N, E);
    bucket_scan_k<<<1, B, 0, stream>>>(bcnt, bbase, bcur, NB, E);
    bucket_scatter_k<<<cdiv(E, B), B, 0, stream>>>(ei, E, bcur, bk, flags);
    final_scatter_k<<<NB, B, 0, stream>>>(bk, bbase, incl, csr, NB);

    // ---------------- Layer 1: 128 -> (2 heads x 64), concat, relu ----------------
    gemm_alpha_mfma_k<0, 128, 2><<<gemmBlocks, 256, 0, stream>>>(x, W1, as1, ad1, hX, as_, ad_, N, flags);
    agg128_k<2, true><<<waveBlocks, 256, 0, stream>>>(hX, as_, ad_, rs, csr, b1, hZ,
                                                      d_out, off_a1, N, flags);

    // ---------------- Layer 2: 128 -> 128, 1 head, mean(=identity), relu ----------------
    gemm_alpha_mfma_k<1, 128, 1><<<gemmBlocks, 256, 0, stream>>>(hZ, W2, as2, ad2, hX, as_, ad_, N, flags);
    agg128_k<1, true><<<waveBlocks, 256, 0, stream>>>(hX, as_, ad_, rs, csr, b2, hZ,
                                                      d_out, off_a2, N, flags);

    // ---------------- Layer 3: 128 -> 16, 1 head, mean(=identity), no relu ----------------
    gemm_alpha_mfma_k<1, 16, 1><<<gemmBlocks, 256, 0, stream>>>(hZ, W3, as3, ad3, h3, as_, ad_, N, flags);
    agg16_k<<<waveBlocks, 256, 0, stream>>>(h3, as_, ad_, rs, csr, bufE,
                                            d_out, off_a3, N, flags);
    zero_f32<<<1, B, 0, stream>>>(g_sum, 256);
    finalize3_k<<<cdiv((long)N * 16, B), B, 0, stream>>>(bufE, b3, batch, d_out, off_emb, g_sum, N, flags);

    // ---------------- Pool + classifier head ----------------
    head_k<<<1, B, 0, stream>>>(g_sum, batch, Wl, bl, d_out, off_gemb, N, flags);
}

// Round 15
// 356.276 us; speedup vs baseline: 1.1791x; 1.1791x over previous
//
#include <hip/hip_runtime.h>
#include <hip/hip_bf16.h>

#define DEVFN __device__ __forceinline__

using short8 = __attribute__((ext_vector_type(8))) short;
using f32x4  = __attribute__((ext_vector_type(4))) float;

// ---- dual-dtype helpers: flags[0]=1 -> floats are f32 (else bf16);
//                          flags[1]=1 -> ints are int64 (else int32)
DEVFN float ldf(const void* p, size_t i, bool f32) {
    return f32 ? ((const float*)p)[i]
               : __bfloat162float(((const __hip_bfloat16*)p)[i]);
}
DEVFN int ldidx(const void* p, size_t i, bool i64) {
    return i64 ? (int)((const long long*)p)[i] : ((const int*)p)[i];
}
DEVFN void stf(void* p, size_t i, float v, bool f32) {
    if (f32) ((float*)p)[i] = v;
    else     ((__hip_bfloat16*)p)[i] = __float2bfloat16(v);
}
DEVFN float lky(float v) { return v > 0.f ? v : 0.2f * v; }

// raw-bits bf16 <-> f32
DEVFN float bfbits2f(short s) {
    return __uint_as_float(((unsigned)(unsigned short)s) << 16);
}
DEVFN short f2bfbits(float f) {  // RNE, finite inputs
    unsigned u = __float_as_uint(f);
    return (short)((u + 0x7fffu + ((u >> 16) & 1u)) >> 16);
}

__global__ void detect_k(const void* x, const void* ei, int* flags) {
    if (threadIdx.x == 0 && blockIdx.x == 0) {
        const __hip_bfloat16* xb = (const __hip_bfloat16*)x;
        int bad = 0;
        for (int i = 0; i < 512; ++i) {
            float v = __bfloat162float(xb[i]);
            if (!(v == v) || fabsf(v) > 1.0e6f) bad++;
        }
        flags[0] = (bad > 16) ? 1 : 0;
        const unsigned* w = (const unsigned*)ei;
        int zeros = 0;
        for (int i = 0; i < 64; ++i) if (w[2 * i + 1] == 0u) zeros++;
        flags[1] = (zeros >= 60) ? 1 : 0;
    }
}

__global__ void zero_i32(int* __restrict__ p, int n) {
    int i = blockIdx.x * blockDim.x + threadIdx.x;
    int st = gridDim.x * blockDim.x;
    for (; i < n; i += st) p[i] = 0;
}
__global__ void zero_f32(float* __restrict__ p, long n) {
    long i = (long)blockIdx.x * blockDim.x + threadIdx.x;
    long st = (long)gridDim.x * blockDim.x;
    for (; i < n; i += st) p[i] = 0.f;
}

// ---------------- CSR build (dst-sorted, packed {src, eid}) ----------------
__global__ void hist_k(const void* __restrict__ ei, int E, int* __restrict__ cnt,
                       const int* __restrict__ flags) {
    const bool i64 = flags[1] != 0;
    int e = blockIdx.x * blockDim.x + threadIdx.x;
    if (e >= E) return;
    atomicAdd(&cnt[ldidx(ei, (size_t)E + e, i64)], 1);
}

__global__ void scan_block_k(const int* __restrict__ cnt, int* __restrict__ incl,
                             int* __restrict__ part, int N) {
    __shared__ int sm[256];
    int tid = threadIdx.x;
    int i = blockIdx.x * 256 + tid;
    int v = (i < N) ? cnt[i] : 0;
    sm[tid] = v;
    __syncthreads();
    for (int o = 1; o < 256; o <<= 1) {
        int t = (tid >= o) ? sm[tid - o] : 0;
        __syncthreads();
        sm[tid] += t;
        __syncthreads();
    }
    if (i < N) incl[i] = sm[tid];
    if (tid == 255) part[blockIdx.x] = sm[255];
}

__global__ void scan_part_k(int* __restrict__ part, int nb) {
    __shared__ int sm[256];
    __shared__ int off;
    int tid = threadIdx.x;
    if (tid == 0) off = 0;
    __syncthreads();
    for (int b = 0; b < nb; b += 256) {
        int i = b + tid;
        int v = (i < nb) ? part[i] : 0;
        sm[tid] = v;
        __syncthreads();
        for (int o = 1; o < 256; o <<= 1) {
            int t = (tid >= o) ? sm[tid - o] : 0;
            __syncthreads();
            sm[tid] += t;
            __syncthreads();
        }
        if (i < nb) part[i] = sm[tid] - v + off;
        __syncthreads();
        if (tid == 255) off += sm[255];
        __syncthreads();
    }
}

__global__ void finalize_scan_k(int* __restrict__ incl_cur, const int* __restrict__ cnt,
                                const int* __restrict__ part, int* __restrict__ rs,
                                int N, int E) {
    int i = blockIdx.x * 256 + threadIdx.x;
    if (i >= N) return;
    int v = incl_cur[i] - cnt[i] + part[blockIdx.x];
    rs[i] = v;
    incl_cur[i] = v;
    if (i == N - 1) rs[N] = E;
}

__global__ void scatter_csr_k(const void* __restrict__ ei, int E, int* __restrict__ cur,
                              long long* __restrict__ csr64, const int* __restrict__ flags) {
    const bool i64 = flags[1] != 0;
    int e = blockIdx.x * blockDim.x + threadIdx.x;
    if (e >= E) return;
    int s = ldidx(ei, e, i64);
    int d = ldidx(ei, (size_t)E + e, i64);
    int p = atomicAdd(&cur[d], 1);
    // pack {src=lo32, eid=hi32}: little-endian layout == int2{.x=s,.y=e}
    long long v = ((long long)e << 32) | (unsigned)s;
    __builtin_nontemporal_store(v, &csr64[p]);  // nt: don't retain line
}

// ---------------- MFMA GEMM: h = A @ W, fused alpha dots (verbatim round 6/7) ----------------
template <int DSRC, int FOUT, int HEADS>
__global__ __launch_bounds__(256) void gemm_alpha_mfma_k(
    const void* __restrict__ xin, const void* __restrict__ Wv,
    const void* __restrict__ asv, const void* __restrict__ adv,
    short* __restrict__ h_bf, float* __restrict__ as_out, float* __restrict__ ad_out,
    int N, const int* __restrict__ flags)
{
    constexpr int FIN = 128;
    constexpr int NCT = FOUT / 16;
    constexpr int CPH = FOUT / HEADS;
    constexpr int CTPH = CPH / 16;
    const bool f32 = flags[0] != 0;

    __shared__ short Wt[FOUT * FIN];    // swizzled, col-major

    for (int i = threadIdx.x; i < FIN * FOUT; i += 256) {
        int k = i / FOUT, c = i - (i / FOUT) * FOUT;
        short w;
        if (f32) w = f2bfbits(((const float*)Wv)[i]);
        else     w = ((const short*)Wv)[i];
        *(short*)((char*)Wt + (size_t)c * (FIN * 2) + (((k * 2) ^ ((c & 7) << 4)))) = w;
    }
    __syncthreads();

    const int wv = threadIdx.x >> 6;
    const int lane = threadIdx.x & 63;
    const int m0 = blockIdx.x * 64 + wv * 16;
    if (m0 >= N) return;
    const int lrow = lane & 15;
    const int lk   = lane >> 4;

    short8 afrag[4];
    if (DSRC == 0 && f32) {
        const float* xf = (const float*)xin + (size_t)(m0 + lrow) * FIN + lk * 8;
#pragma unroll
        for (int ks = 0; ks < 4; ++ks) {
            short8 t;
#pragma unroll
            for (int j = 0; j < 8; ++j) t[j] = f2bfbits(xf[ks * 32 + j]);
            afrag[ks] = t;
        }
    } else {
        const short* xb = (const short*)xin + (size_t)(m0 + lrow) * FIN + lk * 8;
#pragma unroll
        for (int ks = 0; ks < 4; ++ks)
            afrag[ks] = *(const short8*)(xb + ks * 32);
    }

    float csA[HEADS][4], cdA[HEADS][4];
#pragma unroll
    for (int hd = 0; hd < HEADS; ++hd)
#pragma unroll
        for (int r = 0; r < 4; ++r) { csA[hd][r] = 0.f; cdA[hd][r] = 0.f; }

#pragma unroll
    for (int ct = 0; ct < NCT; ++ct) {
        const int col = ct * 16 + lrow;
        const int hd = ct / CTPH;
        f32x4 acc = {0.f, 0.f, 0.f, 0.f};
#pragma unroll
        for (int ks = 0; ks < 4; ++ks) {
            const int kbyte = ks * 64 + lk * 16;
            short8 bfrag = *(const short8*)((const char*)Wt +
                               (size_t)col * (FIN * 2) + (kbyte ^ ((col & 7) << 4)));
            acc = __builtin_amdgcn_mfma_f32_16x16x32_bf16(afrag[ks], bfrag, acc, 0, 0, 0);
        }
        const float asc = ldf(asv, col, f32);
        const float adc = ldf(adv, col, f32);
#pragma unroll
        for (int r = 0; r < 4; ++r) {
            h_bf[(size_t)(m0 + lk * 4 + r) * FOUT + col] = f2bfbits(acc[r]);
            csA[hd][r] += acc[r] * asc;
            cdA[hd][r] += acc[r] * adc;
        }
    }

#pragma unroll
    for (int hd = 0; hd < HEADS; ++hd)
#pragma unroll
        for (int r = 0; r < 4; ++r) {
            float cs = csA[hd][r], cd = cdA[hd][r];
            for (int o = 1; o < 16; o <<= 1) {
                cs += __shfl_xor(cs, o);
                cd += __shfl_xor(cd, o);
            }
            csA[hd][r] = cs; cdA[hd][r] = cd;
        }
    if (lrow == 0) {
#pragma unroll
        for (int r = 0; r < 4; ++r) {
            int n = m0 + lk * 4 + r;
#pragma unroll
            for (int hd = 0; hd < HEADS; ++hd) {
                as_out[(size_t)n * HEADS + hd] = csA[hd][r];
                ad_out[(size_t)n * HEADS + hd] = cdA[hd][r];
            }
        }
    }
}

// ---------------- FUSED softmax + pull, FOUT=128, wave per node ----------------
// (round 11 structure; HEADS==2 branches are `if constexpr` so the HEADS==1
//  instantiation never type-checks ls_a[wv][1][...])
template <int HEADS, bool RELU>
__global__ __launch_bounds__(256) void agg128_k(
    const short* __restrict__ h_bf, const float* __restrict__ as_,
    const float* __restrict__ ad_, const int* __restrict__ rs,
    const int2* __restrict__ csr, const void* __restrict__ bias,
    short* __restrict__ z_bf, void* __restrict__ dout, size_t aoff,
    int N, const int* __restrict__ flags)
{
    __shared__ int   ls_src[4][64];
    __shared__ float ls_a[4][HEADS][64];
    const bool f32 = flags[0] != 0;
    const int wv = threadIdx.x >> 6;
    const int wid = (blockIdx.x * 256 + threadIdx.x) >> 6;
    if (wid >= N) return;
    const int lane = threadIdx.x & 63;
    const int beg = rs[wid], end = rs[wid + 1];
    const int deg = end - beg;
    const int cg = lane & 15;     // col-group: cols cg*8 .. cg*8+7
    const int es = lane >> 4;     // edge slot 0..3
    const int h = (HEADS == 2) ? (cg >> 3) : 0;

    const float ad0 = ad_[(size_t)wid * HEADS];
    float ad1 = 0.f;
    if constexpr (HEADS == 2) ad1 = ad_[(size_t)wid * 2 + 1];

    float acc[8] = {0.f, 0.f, 0.f, 0.f, 0.f, 0.f, 0.f, 0.f};

    if (deg <= 64) {
        const bool act = lane < deg;
        int2 se = make_int2(0, 0);
        if (act) se = csr[beg + lane];
        float l0 = act ? lky(as_[(size_t)se.x * HEADS] + ad0) : -1e30f;
        float l1 = -1e30f;
        if constexpr (HEADS == 2) l1 = act ? lky(as_[(size_t)se.x * 2 + 1] + ad1) : -1e30f;

        float m0 = l0, m1 = l1;
        for (int o = 1; o < 64; o <<= 1) {
            m0 = fmaxf(m0, __shfl_xor(m0, o));
            if constexpr (HEADS == 2) m1 = fmaxf(m1, __shfl_xor(m1, o));
        }
        float e0 = act ? expf(l0 - m0) : 0.f;
        float e1 = 0.f;
        if constexpr (HEADS == 2) e1 = act ? expf(l1 - m1) : 0.f;
        float s0 = e0, s1 = e1;
        for (int o = 1; o < 64; o <<= 1) {
            s0 += __shfl_xor(s0, o);
            if constexpr (HEADS == 2) s1 += __shfl_xor(s1, o);
        }
        if (act) {
            float a0 = e0 * (1.f / (s0 + 1e-16f));
            ls_src[wv][lane] = se.x;
            ls_a[wv][0][lane] = a0;
            stf(dout, aoff + (size_t)se.y * HEADS, a0, f32);
            if constexpr (HEADS == 2) {
                float a1 = e1 * (1.f / (s1 + 1e-16f));
                ls_a[wv][HEADS - 1][lane] = a1;
                stf(dout, aoff + (size_t)se.y * 2 + 1, a1, f32);
            }
        }
        for (int b = 0; b < deg; b += 8) {
            const int pA = b + es, pB = b + 4 + es;
            int sA = 0, sB = 0;
            float aA = 0.f, aB = 0.f;
            if (pA < deg) { sA = ls_src[wv][pA]; aA = ls_a[wv][h][pA]; }
            if (pB < deg) { sB = ls_src[wv][pB]; aB = ls_a[wv][h][pB]; }
            const short8 hA = *(const short8*)(h_bf + (size_t)sA * 128 + cg * 8);
            const short8 hB = *(const short8*)(h_bf + (size_t)sB * 128 + cg * 8);
#pragma unroll
            for (int j = 0; j < 8; ++j) acc[j] = fmaf(bfbits2f(hA[j]), aA, acc[j]);
#pragma unroll
            for (int j = 0; j < 8; ++j) acc[j] = fmaf(bfbits2f(hB[j]), aB, acc[j]);
        }
    } else {
        float m0 = -1e30f, m1 = -1e30f;
        for (int p = beg + lane; p < end; p += 64) {
            int s = csr[p].x;
            m0 = fmaxf(m0, lky(as_[(size_t)s * HEADS] + ad0));
            if constexpr (HEADS == 2) m1 = fmaxf(m1, lky(as_[(size_t)s * 2 + 1] + ad1));
        }
        for (int o = 1; o < 64; o <<= 1) {
            m0 = fmaxf(m0, __shfl_xor(m0, o));
            if constexpr (HEADS == 2) m1 = fmaxf(m1, __shfl_xor(m1, o));
        }
        float s0 = 0.f, s1 = 0.f;
        for (int p = beg + lane; p < end; p += 64) {
            int s = csr[p].x;
            s0 += expf(lky(as_[(size_t)s * HEADS] + ad0) - m0);
            if constexpr (HEADS == 2) s1 += expf(lky(as_[(size_t)s * 2 + 1] + ad1) - m1);
        }
        for (int o = 1; o < 64; o <<= 1) {
            s0 += __shfl_xor(s0, o);
            if constexpr (HEADS == 2) s1 += __shfl_xor(s1, o);
        }
        const float inv0 = 1.f / (s0 + 1e-16f);
        const float inv1 = 1.f / (s1 + 1e-16f);

        for (int cb = beg; cb < end; cb += 64) {
            const int cn = min(64, end - cb);
            if (lane < cn) {
                int2 se = csr[cb + lane];
                float a0 = expf(lky(as_[(size_t)se.x * HEADS] + ad0) - m0) * inv0;
                ls_src[wv][lane] = se.x;
                ls_a[wv][0][lane] = a0;
                stf(dout, aoff + (size_t)se.y * HEADS, a0, f32);
                if constexpr (HEADS == 2) {
                    float a1 = expf(lky(as_[(size_t)se.x * 2 + 1] + ad1) - m1) * inv1;
                    ls_a[wv][HEADS - 1][lane] = a1;
                    stf(dout, aoff + (size_t)se.y * 2 + 1, a1, f32);
                }
            }
            for (int b = 0; b < cn; b += 8) {
                const int pA = b + es, pB = b + 4 + es;
                int sA = 0, sB = 0;
                float aA = 0.f, aB = 0.f;
                if (pA < cn) { sA = ls_src[wv][pA]; aA = ls_a[wv][h][pA]; }
                if (pB < cn) { sB = ls_src[wv][pB]; aB = ls_a[wv][h][pB]; }
                const short8 hA = *(const short8*)(h_bf + (size_t)sA * 128 + cg * 8);
                const short8 hB = *(const short8*)(h_bf + (size_t)sB * 128 + cg * 8);
#pragma unroll
                for (int j = 0; j < 8; ++j) acc[j] = fmaf(bfbits2f(hA[j]), aA, acc[j]);
#pragma unroll
                for (int j = 0; j < 8; ++j) acc[j] = fmaf(bfbits2f(hB[j]), aB, acc[j]);
            }
        }
    }

#pragma unroll
    for (int j = 0; j < 8; ++j) {
        acc[j] += __shfl_xor(acc[j], 16);
        acc[j] += __shfl_xor(acc[j], 32);
    }
    if (es == 0) {
        short8 outv;
#pragma unroll
        for (int j = 0; j < 8; ++j) {
            float v = acc[j] + ldf(bias, cg * 8 + j, f32);
            if (RELU) v = fmaxf(v, 0.f);
            outv[j] = f2bfbits(v);
        }
        *(short8*)(z_bf + (size_t)wid * 128 + cg * 8) = outv;
    }
}

// ---------------- FUSED softmax + pull, FOUT=16, wave per node (verbatim round 11) ----------------
__global__ __launch_bounds__(256) void agg16_k(
    const short* __restrict__ h_bf, const float* __restrict__ as_,
    const float* __restrict__ ad_, const int* __restrict__ rs,
    const int2* __restrict__ csr, float* __restrict__ out,
    void* __restrict__ dout, size_t aoff, int N, const int* __restrict__ flags)
{
    __shared__ int   ls_src[4][64];
    __shared__ float ls_a[4][64];
    const bool f32 = flags[0] != 0;
    const int wv = threadIdx.x >> 6;
    const int wid = (blockIdx.x * 256 + threadIdx.x) >> 6;
    if (wid >= N) return;
    const int lane = threadIdx.x & 63;
    const int beg = rs[wid], end = rs[wid + 1];
    const int deg = end - beg;
    const int cg = lane & 7;      // cols cg*2, cg*2+1
    const int es = lane >> 3;     // edge slot 0..7

    const float ad0 = ad_[wid];

    float a0s = 0.f, a1s = 0.f;

    if (deg <= 64) {
        const bool act = lane < deg;
        int2 se = make_int2(0, 0);
        if (act) se = csr[beg + lane];
        float l0 = act ? lky(as_[se.x] + ad0) : -1e30f;
        float m0 = l0;
        for (int o = 1; o < 64; o <<= 1) m0 = fmaxf(m0, __shfl_xor(m0, o));
        float e0 = act ? expf(l0 - m0) : 0.f;
        float s0 = e0;
        for (int o = 1; o < 64; o <<= 1) s0 += __shfl_xor(s0, o);
        if (act) {
            float a0 = e0 * (1.f / (s0 + 1e-16f));
            ls_src[wv][lane] = se.x;
            ls_a[wv][lane] = a0;
            stf(dout, aoff + se.y, a0, f32);
        }
        for (int b = 0; b < deg; b += 8) {
            const int p = b + es;
            if (p < deg) {
                const int sj = ls_src[wv][p];
                const float a = ls_a[wv][p];
                const int hv = *(const int*)(h_bf + (size_t)sj * 16 + cg * 2);
                a0s = fmaf(bfbits2f((short)(hv & 0xffff)), a, a0s);
                a1s = fmaf(bfbits2f((short)(hv >> 16)), a, a1s);
            }
        }
    } else {
        float m0 = -1e30f;
        for (int p = beg + lane; p < end; p += 64)
            m0 = fmaxf(m0, lky(as_[csr[p].x] + ad0));
        for (int o = 1; o < 64; o <<= 1) m0 = fmaxf(m0, __shfl_xor(m0, o));
        float s0 = 0.f;
        for (int p = beg + lane; p < end; p += 64)
            s0 += expf(lky(as_[csr[p].x] + ad0) - m0);
        for (int o = 1; o < 64; o <<= 1) s0 += __shfl_xor(s0, o);
        const float inv0 = 1.f / (s0 + 1e-16f);

        for (int cb = beg; cb < end; cb += 64) {
            const int cn = min(64, end - cb);
            if (lane < cn) {
                int2 se = csr[cb + lane];
                float a0 = expf(lky(as_[se.x] + ad0) - m0) * inv0;
                ls_src[wv][lane] = se.x;
                ls_a[wv][lane] = a0;
                stf(dout, aoff + se.y, a0, f32);
            }
            for (int b = 0; b < cn; b += 8) {
                const int p = b + es;
                if (p < cn) {
                    const int sj = ls_src[wv][p];
                    const float a = ls_a[wv][p];
                    const int hv = *(const int*)(h_bf + (size_t)sj * 16 + cg * 2);
                    a0s = fmaf(bfbits2f((short)(hv & 0xffff)), a, a0s);
                    a1s = fmaf(bfbits2f((short)(hv >> 16)), a, a1s);
                }
            }
        }
    }

#pragma unroll
    for (int o = 8; o < 64; o <<= 1) {
        a0s += __shfl_xor(a0s, o);
        a1s += __shfl_xor(a1s, o);
    }
    if (es == 0) {
        out[(size_t)wid * 16 + cg * 2]     = a0s;
        out[(size_t)wid * 16 + cg * 2 + 1] = a1s;
    }
}

// layer3 finalize: emb = acc + b3, write emb to d_out, pool per-graph sums
__global__ __launch_bounds__(256) void finalize3_k(
    const float* __restrict__ acc, const void* __restrict__ bias,
    const void* __restrict__ batch, void* __restrict__ dout, size_t emb_off,
    float* __restrict__ g_sum, int N, const int* __restrict__ flags)
{
    const bool f32 = flags[0] != 0;
    const bool i64 = flags[1] != 0;
    __shared__ float gp[256];
    int tid = threadIdx.x;
    gp[tid] = 0.f;
    __syncthreads();
    long idx = (long)blockIdx.x * 256 + tid;
    if (idx < (long)N * 16) {
        int n = (int)(idx >> 4), col = (int)(idx & 15);
        float v = acc[idx] + ldf(bias, col, f32);
        stf(dout, emb_off + idx, v, f32);
        int g = ldidx(batch, n, i64);
        atomicAdd(&gp[g * 16 + col], v);
    }
    __syncthreads();
    float pv = gp[tid];
    if (pv != 0.f) atomicAdd(&g_sum[tid], pv);
}

__global__ __launch_bounds__(256) void head_k(
    const float* __restrict__ g_sum, const void* __restrict__ batch,
    const void* __restrict__ Wl, const void* __restrict__ bl,
    void* __restrict__ dout, size_t gemb_off, int N, const int* __restrict__ flags)
{
    const bool f32 = flags[0] != 0;
    const bool i64 = flags[1] != 0;
    __shared__ float ge[256];
    __shared__ int cnts[16];
    int tid = threadIdx.x;
    if (tid < 16) {
        int lo = 0, hi = N;
        while (lo < hi) { int mid = (lo + hi) >> 1; if (ldidx(batch, mid, i64) < tid) lo = mid + 1; else hi = mid; }
        int l2 = 0, h2 = N;
        while (l2 < h2) { int mid = (l2 + h2) >> 1; if (ldidx(batch, mid, i64) <= tid) l2 = mid + 1; else h2 = mid; }
        cnts[tid] = l2 - lo;
    }
    __syncthreads();
    {
        int g = tid >> 4;
        float v = g_sum[tid] / fmaxf((float)cnts[g], 1.f);
        ge[tid] = v;
        stf(dout, gemb_off + tid, v, f32);
    }
    __syncthreads();
    if (tid < 32) {
        int g = tid >> 1, j = tid & 1;
        float s = ldf(bl, j, f32);
        for (int c = 0; c < 16; ++c) s += ge[g * 16 + c] * ldf(Wl, (size_t)c * 2 + j, f32);
        stf(dout, (size_t)g * 2 + j, s, f32);
    }
}

static inline int cdiv(long a, int b) { return (int)((a + b - 1) / b); }

extern "C" void kernel_launch(void* const* d_in, const int* in_sizes, int n_in,
                              void* d_out, int out_size, void* d_ws, size_t ws_size,
                              hipStream_t stream)
{
    const void* x   = d_in[0];
    const void* ei  = d_in[1];
    const void* batch = d_in[2];
    const void* W1  = d_in[3];
    const void* as1 = d_in[4];
    const void* ad1 = d_in[5];
    const void* b1  = d_in[6];
    const void* W2  = d_in[7];
    const void* as2 = d_in[8];
    const void* ad2 = d_in[9];
    const void* b2  = d_in[10];
    const void* W3  = d_in[11];
    const void* as3 = d_in[12];
    const void* ad3 = d_in[13];
    const void* b3  = d_in[14];
    const void* Wl  = d_in[15];
    const void* bl  = d_in[16];

    const int N = in_sizes[0] / 128;
    const int E = in_sizes[1] / 2;

    int* flags = (int*)d_ws;
    float* ws = (float*)d_ws + 16;
    size_t o = 0;
    float* as_  = ws + o; o += (size_t)N * 2;
    float* ad_  = ws + o; o += (size_t)N * 2;
    float* bufE = ws + o; o += (size_t)N * 16;
    float* g_sum = ws + o; o += 256;
    short* hX = (short*)(ws + o); o += (size_t)N * 64;  // h (bf16), gemm out
    short* hZ = (short*)(ws + o); o += (size_t)N * 64;  // z (bf16), agg out
    short* h3 = (short*)(ws + o); o += (size_t)N * 8;   // layer3 h (bf16)
    int* ip = (int*)(ws + o);
    int* cnt  = ip;            ip += N;
    int* incl = ip;            ip += N;   // reused as `cur` after finalize_scan
    int* part = ip;            ip += 256;
    int* rs   = ip;            ip += N + 1;
    if (((uintptr_t)ip & 7) != 0) ip += 1;   // align int2/long long
    int2* csr = (int2*)ip;     ip += 2 * E;  // packed {src, eid}, dst-sorted

    const size_t off_gemb = 32;
    const size_t off_emb  = 32 + 256;
    const size_t off_a1   = off_emb + (size_t)N * 16;
    const size_t off_a2   = off_a1 + (size_t)E * 2;
    const size_t off_a3   = off_a2 + (size_t)E;

    const int B = 256;
    const int nbN = cdiv(N, 256);
    const int gemmBlocks = cdiv(N, 64);
    const int waveBlocks = cdiv(N, 4);   // 4 waves (nodes) per 256-thr block

    detect_k<<<1, 64, 0, stream>>>(x, ei, flags);

    // ---- CSR build (dst-sorted packed {src,eid}), reused by all layers ----
    zero_i32<<<nbN, B, 0, stream>>>(cnt, N);
    hist_k<<<cdiv(E, B), B, 0, stream>>>(ei, E, cnt, flags);
    scan_block_k<<<nbN, B, 0, stream>>>(cnt, incl, part, N);
    scan_part_k<<<1, B, 0, stream>>>(part, nbN);
    finalize_scan_k<<<nbN, B, 0, stream>>>(incl, cnt, part, rs, N, E);
    scatter_csr_k<<<cdiv(E, B), B, 0, stream>>>(ei, E, incl, (long long*)csr, flags);

    // ---------------- Layer 1: 128 -> (2 heads x 64), concat, relu ----------------
    gemm_alpha_mfma_k<0, 128, 2><<<gemmBlocks, 256, 0, stream>>>(x, W1, as1, ad1, hX, as_, ad_, N, flags);
    agg128_k<2, true><<<waveBlocks, 256, 0, stream>>>(hX, as_, ad_, rs, csr, b1, hZ,
                                                      d_out, off_a1, N, flags);

    // ---------------- Layer 2: 128 -> 128, 1 head, mean(=identity), relu ----------------
    gemm_alpha_mfma_k<1, 128, 1><<<gemmBlocks, 256, 0, stream>>>(hZ, W2, as2, ad2, hX, as_, ad_, N, flags);
    agg128_k<1, true><<<waveBlocks, 256, 0, stream>>>(hX, as_, ad_, rs, csr, b2, hZ,
                                                      d_out, off_a2, N, flags);

    // ---------------- Layer 3: 128 -> 16, 1 head, mean(=identity), no relu ----------------
    gemm_alpha_mfma_k<1, 16, 1><<<gemmBlocks, 256, 0, stream>>>(hZ, W3, as3, ad3, h3, as_, ad_, N, flags);
    agg16_k<<<waveBlocks, 256, 0, stream>>>(h3, as_, ad_, rs, csr, bufE,
                                            d_out, off_a3, N, flags);
    zero_f32<<<1, B, 0, stream>>>(g_sum, 256);
    finalize3_k<<<cdiv((long)N * 16, B), B, 0, stream>>>(bufE, b3, batch, d_out, off_emb, g_sum, N, flags);

    // ---------------- Pool + classifier head ----------------
    head_k<<<1, B, 0, stream>>>(g_sum, batch, Wl, bl, d_out, off_gemb, N, flags);
}

// Round 16
// 348.712 us; speedup vs baseline: 1.2047x; 1.0217x over previous
//
#include <hip/hip_runtime.h>
#include <hip/hip_bf16.h>

#define DEVFN __device__ __forceinline__

using short8 = __attribute__((ext_vector_type(8))) short;
using f32x4  = __attribute__((ext_vector_type(4))) float;

// ---- dual-dtype helpers: flags[0]=1 -> floats are f32 (else bf16);
//                          flags[1]=1 -> ints are int64 (else int32)
DEVFN float ldf(const void* p, size_t i, bool f32) {
    return f32 ? ((const float*)p)[i]
               : __bfloat162float(((const __hip_bfloat16*)p)[i]);
}
DEVFN int ldidx(const void* p, size_t i, bool i64) {
    return i64 ? (int)((const long long*)p)[i] : ((const int*)p)[i];
}
DEVFN void stf(void* p, size_t i, float v, bool f32) {
    if (f32) ((float*)p)[i] = v;
    else     ((__hip_bfloat16*)p)[i] = __float2bfloat16(v);
}
DEVFN float lky(float v) { return v > 0.f ? v : 0.2f * v; }

// raw-bits bf16 <-> f32
DEVFN float bfbits2f(short s) {
    return __uint_as_float(((unsigned)(unsigned short)s) << 16);
}
DEVFN short f2bfbits(float f) {  // RNE, finite inputs
    unsigned u = __float_as_uint(f);
    return (short)((u + 0x7fffu + ((u >> 16) & 1u)) >> 16);
}

__global__ void detect_k(const void* x, const void* ei, int* flags) {
    if (threadIdx.x == 0 && blockIdx.x == 0) {
        const __hip_bfloat16* xb = (const __hip_bfloat16*)x;
        int bad = 0;
        for (int i = 0; i < 512; ++i) {
            float v = __bfloat162float(xb[i]);
            if (!(v == v) || fabsf(v) > 1.0e6f) bad++;
        }
        flags[0] = (bad > 16) ? 1 : 0;
        const unsigned* w = (const unsigned*)ei;
        int zeros = 0;
        for (int i = 0; i < 64; ++i) if (w[2 * i + 1] == 0u) zeros++;
        flags[1] = (zeros >= 60) ? 1 : 0;
    }
}

__global__ void zero_i32(int* __restrict__ p, int n) {
    int i = blockIdx.x * blockDim.x + threadIdx.x;
    int st = gridDim.x * blockDim.x;
    for (; i < n; i += st) p[i] = 0;
}
__global__ void zero_f32(float* __restrict__ p, long n) {
    long i = (long)blockIdx.x * blockDim.x + threadIdx.x;
    long st = (long)gridDim.x * blockDim.x;
    for (; i < n; i += st) p[i] = 0.f;
}

// ---------------- CSR build (dst-sorted, packed {src, eid}) ----------------
__global__ void hist_k(const void* __restrict__ ei, int E, int* __restrict__ cnt,
                       const int* __restrict__ flags) {
    const bool i64 = flags[1] != 0;
    int e = blockIdx.x * blockDim.x + threadIdx.x;
    if (e >= E) return;
    atomicAdd(&cnt[ldidx(ei, (size_t)E + e, i64)], 1);
}

__global__ void scan_block_k(const int* __restrict__ cnt, int* __restrict__ incl,
                             int* __restrict__ part, int N) {
    __shared__ int sm[256];
    int tid = threadIdx.x;
    int i = blockIdx.x * 256 + tid;
    int v = (i < N) ? cnt[i] : 0;
    sm[tid] = v;
    __syncthreads();
    for (int o = 1; o < 256; o <<= 1) {
        int t = (tid >= o) ? sm[tid - o] : 0;
        __syncthreads();
        sm[tid] += t;
        __syncthreads();
    }
    if (i < N) incl[i] = sm[tid];
    if (tid == 255) part[blockIdx.x] = sm[255];
}

__global__ void scan_part_k(int* __restrict__ part, int nb) {
    __shared__ int sm[256];
    __shared__ int off;
    int tid = threadIdx.x;
    if (tid == 0) off = 0;
    __syncthreads();
    for (int b = 0; b < nb; b += 256) {
        int i = b + tid;
        int v = (i < nb) ? part[i] : 0;
        sm[tid] = v;
        __syncthreads();
        for (int o = 1; o < 256; o <<= 1) {
            int t = (tid >= o) ? sm[tid - o] : 0;
            __syncthreads();
            sm[tid] += t;
            __syncthreads();
        }
        if (i < nb) part[i] = sm[tid] - v + off;
        __syncthreads();
        if (tid == 255) off += sm[255];
        __syncthreads();
    }
}

__global__ void finalize_scan_k(int* __restrict__ incl_cur, const int* __restrict__ cnt,
                                const int* __restrict__ part, int* __restrict__ rs,
                                int N, int E) {
    int i = blockIdx.x * 256 + threadIdx.x;
    if (i >= N) return;
    int v = incl_cur[i] - cnt[i] + part[blockIdx.x];
    rs[i] = v;
    incl_cur[i] = v;
    if (i == N - 1) rs[N] = E;
}

__global__ void scatter_csr_k(const void* __restrict__ ei, int E, int* __restrict__ cur,
                              int2* __restrict__ csr, const int* __restrict__ flags) {
    const bool i64 = flags[1] != 0;
    int e = blockIdx.x * blockDim.x + threadIdx.x;
    if (e >= E) return;
    int s = ldidx(ei, e, i64);
    int d = ldidx(ei, (size_t)E + e, i64);
    int p = atomicAdd(&cur[d], 1);
    csr[p] = make_int2(s, e);   // plain store (nt-store measured slower, R15)
}

// ---------------- MFMA GEMM: h = A @ W, fused alpha dots (verbatim round 6/7) ----------------
template <int DSRC, int FOUT, int HEADS>
__global__ __launch_bounds__(256) void gemm_alpha_mfma_k(
    const void* __restrict__ xin, const void* __restrict__ Wv,
    const void* __restrict__ asv, const void* __restrict__ adv,
    short* __restrict__ h_bf, float* __restrict__ as_out, float* __restrict__ ad_out,
    int N, const int* __restrict__ flags)
{
    constexpr int FIN = 128;
    constexpr int NCT = FOUT / 16;
    constexpr int CPH = FOUT / HEADS;
    constexpr int CTPH = CPH / 16;
    const bool f32 = flags[0] != 0;

    __shared__ short Wt[FOUT * FIN];    // swizzled, col-major

    for (int i = threadIdx.x; i < FIN * FOUT; i += 256) {
        int k = i / FOUT, c = i - (i / FOUT) * FOUT;
        short w;
        if (f32) w = f2bfbits(((const float*)Wv)[i]);
        else     w = ((const short*)Wv)[i];
        *(short*)((char*)Wt + (size_t)c * (FIN * 2) + (((k * 2) ^ ((c & 7) << 4)))) = w;
    }
    __syncthreads();

    const int wv = threadIdx.x >> 6;
    const int lane = threadIdx.x & 63;
    const int m0 = blockIdx.x * 64 + wv * 16;
    if (m0 >= N) return;
    const int lrow = lane & 15;
    const int lk   = lane >> 4;

    short8 afrag[4];
    if (DSRC == 0 && f32) {
        const float* xf = (const float*)xin + (size_t)(m0 + lrow) * FIN + lk * 8;
#pragma unroll
        for (int ks = 0; ks < 4; ++ks) {
            short8 t;
#pragma unroll
            for (int j = 0; j < 8; ++j) t[j] = f2bfbits(xf[ks * 32 + j]);
            afrag[ks] = t;
        }
    } else {
        const short* xb = (const short*)xin + (size_t)(m0 + lrow) * FIN + lk * 8;
#pragma unroll
        for (int ks = 0; ks < 4; ++ks)
            afrag[ks] = *(const short8*)(xb + ks * 32);
    }

    float csA[HEADS][4], cdA[HEADS][4];
#pragma unroll
    for (int hd = 0; hd < HEADS; ++hd)
#pragma unroll
        for (int r = 0; r < 4; ++r) { csA[hd][r] = 0.f; cdA[hd][r] = 0.f; }

#pragma unroll
    for (int ct = 0; ct < NCT; ++ct) {
        const int col = ct * 16 + lrow;
        const int hd = ct / CTPH;
        f32x4 acc = {0.f, 0.f, 0.f, 0.f};
#pragma unroll
        for (int ks = 0; ks < 4; ++ks) {
            const int kbyte = ks * 64 + lk * 16;
            short8 bfrag = *(const short8*)((const char*)Wt +
                               (size_t)col * (FIN * 2) + (kbyte ^ ((col & 7) << 4)));
            acc = __builtin_amdgcn_mfma_f32_16x16x32_bf16(afrag[ks], bfrag, acc, 0, 0, 0);
        }
        const float asc = ldf(asv, col, f32);
        const float adc = ldf(adv, col, f32);
#pragma unroll
        for (int r = 0; r < 4; ++r) {
            h_bf[(size_t)(m0 + lk * 4 + r) * FOUT + col] = f2bfbits(acc[r]);
            csA[hd][r] += acc[r] * asc;
            cdA[hd][r] += acc[r] * adc;
        }
    }

#pragma unroll
    for (int hd = 0; hd < HEADS; ++hd)
#pragma unroll
        for (int r = 0; r < 4; ++r) {
            float cs = csA[hd][r], cd = cdA[hd][r];
            for (int o = 1; o < 16; o <<= 1) {
                cs += __shfl_xor(cs, o);
                cd += __shfl_xor(cd, o);
            }
            csA[hd][r] = cs; cdA[hd][r] = cd;
        }
    if (lrow == 0) {
#pragma unroll
        for (int r = 0; r < 4; ++r) {
            int n = m0 + lk * 4 + r;
#pragma unroll
            for (int hd = 0; hd < HEADS; ++hd) {
                as_out[(size_t)n * HEADS + hd] = csA[hd][r];
                ad_out[(size_t)n * HEADS + hd] = cdA[hd][r];
            }
        }
    }
}

// ---------------- FUSED softmax + pull, FOUT=128, wave per node ----------------
template <int HEADS, bool RELU>
__global__ __launch_bounds__(256) void agg128_k(
    const short* __restrict__ h_bf, const float* __restrict__ as_,
    const float* __restrict__ ad_, const int* __restrict__ rs,
    const int2* __restrict__ csr, const void* __restrict__ bias,
    short* __restrict__ z_bf, void* __restrict__ dout, size_t aoff,
    int N, const int* __restrict__ flags)
{
    __shared__ int   ls_src[4][64];
    __shared__ float ls_a[4][HEADS][64];
    const bool f32 = flags[0] != 0;
    const int wv = threadIdx.x >> 6;
    const int wid = (blockIdx.x * 256 + threadIdx.x) >> 6;
    if (wid >= N) return;
    const int lane = threadIdx.x & 63;
    const int beg = rs[wid], end = rs[wid + 1];
    const int deg = end - beg;
    const int cg = lane & 15;     // col-group: cols cg*8 .. cg*8+7
    const int es = lane >> 4;     // edge slot 0..3
    const int h = (HEADS == 2) ? (cg >> 3) : 0;

    const float ad0 = ad_[(size_t)wid * HEADS];
    float ad1 = 0.f;
    if constexpr (HEADS == 2) ad1 = ad_[(size_t)wid * 2 + 1];

    float acc[8] = {0.f, 0.f, 0.f, 0.f, 0.f, 0.f, 0.f, 0.f};

    if (deg <= 64) {
        const bool act = lane < deg;
        int2 se = make_int2(0, 0);
        if (act) se = csr[beg + lane];
        float l0 = act ? lky(as_[(size_t)se.x * HEADS] + ad0) : -1e30f;
        float l1 = -1e30f;
        if constexpr (HEADS == 2) l1 = act ? lky(as_[(size_t)se.x * 2 + 1] + ad1) : -1e30f;

        float m0 = l0, m1 = l1;
        for (int o = 1; o < 64; o <<= 1) {
            m0 = fmaxf(m0, __shfl_xor(m0, o));
            if constexpr (HEADS == 2) m1 = fmaxf(m1, __shfl_xor(m1, o));
        }
        float e0 = act ? expf(l0 - m0) : 0.f;
        float e1 = 0.f;
        if constexpr (HEADS == 2) e1 = act ? expf(l1 - m1) : 0.f;
        float s0 = e0, s1 = e1;
        for (int o = 1; o < 64; o <<= 1) {
            s0 += __shfl_xor(s0, o);
            if constexpr (HEADS == 2) s1 += __shfl_xor(s1, o);
        }
        if (act) {
            float a0 = e0 * (1.f / (s0 + 1e-16f));
            ls_src[wv][lane] = se.x;
            ls_a[wv][0][lane] = a0;
            stf(dout, aoff + (size_t)se.y * HEADS, a0, f32);
            if constexpr (HEADS == 2) {
                float a1 = e1 * (1.f / (s1 + 1e-16f));
                ls_a[wv][HEADS - 1][lane] = a1;
                stf(dout, aoff + (size_t)se.y * 2 + 1, a1, f32);
            }
        }
        for (int b = 0; b < deg; b += 8) {
            const int pA = b + es, pB = b + 4 + es;
            int sA = 0, sB = 0;
            float aA = 0.f, aB = 0.f;
            if (pA < deg) { sA = ls_src[wv][pA]; aA = ls_a[wv][h][pA]; }
            if (pB < deg) { sB = ls_src[wv][pB]; aB = ls_a[wv][h][pB]; }
            const short8 hA = *(const short8*)(h_bf + (size_t)sA * 128 + cg * 8);
            const short8 hB = *(const short8*)(h_bf + (size_t)sB * 128 + cg * 8);
#pragma unroll
            for (int j = 0; j < 8; ++j) acc[j] = fmaf(bfbits2f(hA[j]), aA, acc[j]);
#pragma unroll
            for (int j = 0; j < 8; ++j) acc[j] = fmaf(bfbits2f(hB[j]), aB, acc[j]);
        }
    } else {
        float m0 = -1e30f, m1 = -1e30f;
        for (int p = beg + lane; p < end; p += 64) {
            int s = csr[p].x;
            m0 = fmaxf(m0, lky(as_[(size_t)s * HEADS] + ad0));
            if constexpr (HEADS == 2) m1 = fmaxf(m1, lky(as_[(size_t)s * 2 + 1] + ad1));
        }
        for (int o = 1; o < 64; o <<= 1) {
            m0 = fmaxf(m0, __shfl_xor(m0, o));
            if constexpr (HEADS == 2) m1 = fmaxf(m1, __shfl_xor(m1, o));
        }
        float s0 = 0.f, s1 = 0.f;
        for (int p = beg + lane; p < end; p += 64) {
            int s = csr[p].x;
            s0 += expf(lky(as_[(size_t)s * HEADS] + ad0) - m0);
            if constexpr (HEADS == 2) s1 += expf(lky(as_[(size_t)s * 2 + 1] + ad1) - m1);
        }
        for (int o = 1; o < 64; o <<= 1) {
            s0 += __shfl_xor(s0, o);
            if constexpr (HEADS == 2) s1 += __shfl_xor(s1, o);
        }
        const float inv0 = 1.f / (s0 + 1e-16f);
        const float inv1 = 1.f / (s1 + 1e-16f);

        for (int cb = beg; cb < end; cb += 64) {
            const int cn = min(64, end - cb);
            if (lane < cn) {
                int2 se = csr[cb + lane];
                float a0 = expf(lky(as_[(size_t)se.x * HEADS] + ad0) - m0) * inv0;
                ls_src[wv][lane] = se.x;
                ls_a[wv][0][lane] = a0;
                stf(dout, aoff + (size_t)se.y * HEADS, a0, f32);
                if constexpr (HEADS == 2) {
                    float a1 = expf(lky(as_[(size_t)se.x * 2 + 1] + ad1) - m1) * inv1;
                    ls_a[wv][HEADS - 1][lane] = a1;
                    stf(dout, aoff + (size_t)se.y * 2 + 1, a1, f32);
                }
            }
            for (int b = 0; b < cn; b += 8) {
                const int pA = b + es, pB = b + 4 + es;
                int sA = 0, sB = 0;
                float aA = 0.f, aB = 0.f;
                if (pA < cn) { sA = ls_src[wv][pA]; aA = ls_a[wv][h][pA]; }
                if (pB < cn) { sB = ls_src[wv][pB]; aB = ls_a[wv][h][pB]; }
                const short8 hA = *(const short8*)(h_bf + (size_t)sA * 128 + cg * 8);
                const short8 hB = *(const short8*)(h_bf + (size_t)sB * 128 + cg * 8);
#pragma unroll
                for (int j = 0; j < 8; ++j) acc[j] = fmaf(bfbits2f(hA[j]), aA, acc[j]);
#pragma unroll
                for (int j = 0; j < 8; ++j) acc[j] = fmaf(bfbits2f(hB[j]), aB, acc[j]);
            }
        }
    }

#pragma unroll
    for (int j = 0; j < 8; ++j) {
        acc[j] += __shfl_xor(acc[j], 16);
        acc[j] += __shfl_xor(acc[j], 32);
    }
    if (es == 0) {
        short8 outv;
#pragma unroll
        for (int j = 0; j < 8; ++j) {
            float v = acc[j] + ldf(bias, cg * 8 + j, f32);
            if (RELU) v = fmaxf(v, 0.f);
            outv[j] = f2bfbits(v);
        }
        *(short8*)(z_bf + (size_t)wid * 128 + cg * 8) = outv;
    }
}

// ---------------- FUSED softmax + pull, FOUT=16, wave per node ----------------
__global__ __launch_bounds__(256) void agg16_k(
    const short* __restrict__ h_bf, const float* __restrict__ as_,
    const float* __restrict__ ad_, const int* __restrict__ rs,
    const int2* __restrict__ csr, float* __restrict__ out,
    void* __restrict__ dout, size_t aoff, int N, const int* __restrict__ flags)
{
    __shared__ int   ls_src[4][64];
    __shared__ float ls_a[4][64];
    const bool f32 = flags[0] != 0;
    const int wv = threadIdx.x >> 6;
    const int wid = (blockIdx.x * 256 + threadIdx.x) >> 6;
    if (wid >= N) return;
    const int lane = threadIdx.x & 63;
    const int beg = rs[wid], end = rs[wid + 1];
    const int deg = end - beg;
    const int cg = lane & 7;      // cols cg*2, cg*2+1
    const int es = lane >> 3;     // edge slot 0..7

    const float ad0 = ad_[wid];

    float a0s = 0.f, a1s = 0.f;

    if (deg <= 64) {
        const bool act = lane < deg;
        int2 se = make_int2(0, 0);
        if (act) se = csr[beg + lane];
        float l0 = act ? lky(as_[se.x] + ad0) : -1e30f;
        float m0 = l0;
        for (int o = 1; o < 64; o <<= 1) m0 = fmaxf(m0, __shfl_xor(m0, o));
        float e0 = act ? expf(l0 - m0) : 0.f;
        float s0 = e0;
        for (int o = 1; o < 64; o <<= 1) s0 += __shfl_xor(s0, o);
        if (act) {
            float a0 = e0 * (1.f / (s0 + 1e-16f));
            ls_src[wv][lane] = se.x;
            ls_a[wv][lane] = a0;
            stf(dout, aoff + se.y, a0, f32);
        }
        for (int b = 0; b < deg; b += 8) {
            const int p = b + es;
            if (p < deg) {
                const int sj = ls_src[wv][p];
                const float a = ls_a[wv][p];
                const int hv = *(const int*)(h_bf + (size_t)sj * 16 + cg * 2);
                a0s = fmaf(bfbits2f((short)(hv & 0xffff)), a, a0s);
                a1s = fmaf(bfbits2f((short)(hv >> 16)), a, a1s);
            }
        }
    } else {
        float m0 = -1e30f;
        for (int p = beg + lane; p < end; p += 64)
            m0 = fmaxf(m0, lky(as_[csr[p].x] + ad0));
        for (int o = 1; o < 64; o <<= 1) m0 = fmaxf(m0, __shfl_xor(m0, o));
        float s0 = 0.f;
        for (int p = beg + lane; p < end; p += 64)
            s0 += expf(lky(as_[csr[p].x] + ad0) - m0);
        for (int o = 1; o < 64; o <<= 1) s0 += __shfl_xor(s0, o);
        const float inv0 = 1.f / (s0 + 1e-16f);

        for (int cb = beg; cb < end; cb += 64) {
            const int cn = min(64, end - cb);
            if (lane < cn) {
                int2 se = csr[cb + lane];
                float a0 = expf(lky(as_[se.x] + ad0) - m0) * inv0;
                ls_src[wv][lane] = se.x;
                ls_a[wv][lane] = a0;
                stf(dout, aoff + se.y, a0, f32);
            }
            for (int b = 0; b < cn; b += 8) {
                const int p = b + es;
                if (p < cn) {
                    const int sj = ls_src[wv][p];
                    const float a = ls_a[wv][p];
                    const int hv = *(const int*)(h_bf + (size_t)sj * 16 + cg * 2);
                    a0s = fmaf(bfbits2f((short)(hv & 0xffff)), a, a0s);
                    a1s = fmaf(bfbits2f((short)(hv >> 16)), a, a1s);
                }
            }
        }
    }

#pragma unroll
    for (int o = 8; o < 64; o <<= 1) {
        a0s += __shfl_xor(a0s, o);
        a1s += __shfl_xor(a1s, o);
    }
    if (es == 0) {
        out[(size_t)wid * 16 + cg * 2]     = a0s;
        out[(size_t)wid * 16 + cg * 2 + 1] = a1s;
    }
}

// layer3 finalize: emb = acc + b3, write emb to d_out, pool per-graph sums
__global__ __launch_bounds__(256) void finalize3_k(
    const float* __restrict__ acc, const void* __restrict__ bias,
    const void* __restrict__ batch, void* __restrict__ dout, size_t emb_off,
    float* __restrict__ g_sum, int N, const int* __restrict__ flags)
{
    const bool f32 = flags[0] != 0;
    const bool i64 = flags[1] != 0;
    __shared__ float gp[256];
    int tid = threadIdx.x;
    gp[tid] = 0.f;
    __syncthreads();
    long idx = (long)blockIdx.x * 256 + tid;
    if (idx < (long)N * 16) {
        int n = (int)(idx >> 4), col = (int)(idx & 15);
        float v = acc[idx] + ldf(bias, col, f32);
        stf(dout, emb_off + idx, v, f32);
        int g = ldidx(batch, n, i64);
        atomicAdd(&gp[g * 16 + col], v);
    }
    __syncthreads();
    float pv = gp[tid];
    if (pv != 0.f) atomicAdd(&g_sum[tid], pv);
}

__global__ __launch_bounds__(256) void head_k(
    const float* __restrict__ g_sum, const void* __restrict__ batch,
    const void* __restrict__ Wl, const void* __restrict__ bl,
    void* __restrict__ dout, size_t gemb_off, int N, const int* __restrict__ flags)
{
    const bool f32 = flags[0] != 0;
    const bool i64 = flags[1] != 0;
    __shared__ float ge[256];
    __shared__ int cnts[16];
    int tid = threadIdx.x;
    if (tid < 16) {
        int lo = 0, hi = N;
        while (lo < hi) { int mid = (lo + hi) >> 1; if (ldidx(batch, mid, i64) < tid) lo = mid + 1; else hi = mid; }
        int l2 = 0, h2 = N;
        while (l2 < h2) { int mid = (l2 + h2) >> 1; if (ldidx(batch, mid, i64) <= tid) l2 = mid + 1; else h2 = mid; }
        cnts[tid] = l2 - lo;
    }
    __syncthreads();
    {
        int g = tid >> 4;
        float v = g_sum[tid] / fmaxf((float)cnts[g], 1.f);
        ge[tid] = v;
        stf(dout, gemb_off + tid, v, f32);
    }
    __syncthreads();
    if (tid < 32) {
        int g = tid >> 1, j = tid & 1;
        float s = ldf(bl, j, f32);
        for (int c = 0; c < 16; ++c) s += ge[g * 16 + c] * ldf(Wl, (size_t)c * 2 + j, f32);
        stf(dout, (size_t)g * 2 + j, s, f32);
    }
}

static inline int cdiv(long a, int b) { return (int)((a + b - 1) / b); }

extern "C" void kernel_launch(void* const* d_in, const int* in_sizes, int n_in,
                              void* d_out, int out_size, void* d_ws, size_t ws_size,
                              hipStream_t stream)
{
    const void* x   = d_in[0];
    const void* ei  = d_in[1];
    const void* batch = d_in[2];
    const void* W1  = d_in[3];
    const void* as1 = d_in[4];
    const void* ad1 = d_in[5];
    const void* b1  = d_in[6];
    const void* W2  = d_in[7];
    const void* as2 = d_in[8];
    const void* ad2 = d_in[9];
    const void* b2  = d_in[10];
    const void* W3  = d_in[11];
    const void* as3 = d_in[12];
    const void* ad3 = d_in[13];
    const void* b3  = d_in[14];
    const void* Wl  = d_in[15];
    const void* bl  = d_in[16];

    const int N = in_sizes[0] / 128;
    const int E = in_sizes[1] / 2;

    int* flags = (int*)d_ws;
    float* ws = (float*)d_ws + 16;
    size_t o = 0;
    float* as_  = ws + o; o += (size_t)N * 2;
    float* ad_  = ws + o; o += (size_t)N * 2;
    float* bufE = ws + o; o += (size_t)N * 16;
    float* g_sum = ws + o; o += 256;
    short* hX = (short*)(ws + o); o += (size_t)N * 64;  // h (bf16), gemm out
    short* hZ = (short*)(ws + o); o += (size_t)N * 64;  // z (bf16), agg out
    short* h3 = (short*)(ws + o); o += (size_t)N * 8;   // layer3 h (bf16)
    int* ip = (int*)(ws + o);
    int* cnt  = ip;            ip += N;
    int* incl = ip;            ip += N;   // reused as `cur` after finalize_scan
    int* part = ip;            ip += 256;
    int* rs   = ip;            ip += N + 1;
    if (((uintptr_t)ip & 7) != 0) ip += 1;   // align int2
    int2* csr = (int2*)ip;     ip += 2 * E;  // packed {src, eid}, dst-sorted

    const size_t off_gemb = 32;
    const size_t off_emb  = 32 + 256;
    const size_t off_a1   = off_emb + (size_t)N * 16;
    const size_t off_a2   = off_a1 + (size_t)E * 2;
    const size_t off_a3   = off_a2 + (size_t)E;

    const int B = 256;
    const int nbN = cdiv(N, 256);
    const int gemmBlocks = cdiv(N, 64);
    const int waveBlocks = cdiv(N, 4);   // 4 waves (nodes) per 256-thr block

    detect_k<<<1, 64, 0, stream>>>(x, ei, flags);

    // ---- CSR build (dst-sorted packed {src,eid}), reused by all layers ----
    zero_i32<<<nbN, B, 0, stream>>>(cnt, N);
    hist_k<<<cdiv(E, B), B, 0, stream>>>(ei, E, cnt, flags);
    scan_block_k<<<nbN, B, 0, stream>>>(cnt, incl, part, N);
    scan_part_k<<<1, B, 0, stream>>>(part, nbN);
    finalize_scan_k<<<nbN, B, 0, stream>>>(incl, cnt, part, rs, N, E);
    scatter_csr_k<<<cdiv(E, B), B, 0, stream>>>(ei, E, incl, csr, flags);

    // ---------------- Layer 1: 128 -> (2 heads x 64), concat, relu ----------------
    gemm_alpha_mfma_k<0, 128, 2><<<gemmBlocks, 256, 0, stream>>>(x, W1, as1, ad1, hX, as_, ad_, N, flags);
    agg128_k<2, true><<<waveBlocks, 256, 0, stream>>>(hX, as_, ad_, rs, csr, b1, hZ,
                                                      d_out, off_a1, N, flags);

    // ---------------- Layer 2: 128 -> 128, 1 head, mean(=identity), relu ----------------
    gemm_alpha_mfma_k<1, 128, 1><<<gemmBlocks, 256, 0, stream>>>(hZ, W2, as2, ad2, hX, as_, ad_, N, flags);
    agg128_k<1, true><<<waveBlocks, 256, 0, stream>>>(hX, as_, ad_, rs, csr, b2, hZ,
                                                      d_out, off_a2, N, flags);

    // ---------------- Layer 3: 128 -> 16, 1 head, mean(=identity), no relu ----------------
    gemm_alpha_mfma_k<1, 16, 1><<<gemmBlocks, 256, 0, stream>>>(hZ, W3, as3, ad3, h3, as_, ad_, N, flags);
    agg16_k<<<waveBlocks, 256, 0, stream>>>(h3, as_, ad_, rs, csr, bufE,
                                            d_out, off_a3, N, flags);
    zero_f32<<<1, B, 0, stream>>>(g_sum, 256);
    finalize3_k<<<cdiv((long)N * 16, B), B, 0, stream>>>(bufE, b3, batch, d_out, off_emb, g_sum, N, flags);

    // ---------------- Pool + classifier head ----------------
    head_k<<<1, B, 0, stream>>>(g_sum, batch, Wl, bl, d_out, off_gemb, N, flags);
}